// Round 23
// baseline (492.930 us; speedup 1.0000x reference)
//
#include <hip/hip_runtime.h>
#include <hip/hip_bf16.h>

// MultiViewFusion — round 23: T14 async-stage prefetch in k_s12g.
// Evidence ledger:
//   R5 PASS scalar. R6-R9 FAIL: MFMA acc->LDS->read corrupts; QUARANTINE:
//   MFMA acc exits only via VALU->global. Scalar data in LDS fine.
//   R20 PASS 500us (gate fold). R21 PASS 420us (best; ff MFMA + k_ln).
//   R22 PASS 437us: 32KB-LDS/4-pass k_s12g = 288us, occupancy UNCHANGED 23%
//   (LDS not the limiter; VGPR-capped) -> k_s12g is latency-bound on the
//   serial stage->barrier->MFMA chain.
// R23: k_s12g with register prefetch (T14): prologue loads pass0; per pass
//   {write LDS, issue pass p+1 loads into 2nd reg set, barrier, MFMA} —
//   load latency hides under the 128-MFMA compute phase. Fully unrolled,
//   compile-time reg indexing. Same values/K-order -> bit-identical output.

namespace {

typedef __attribute__((ext_vector_type(8))) short short8v;   // 8 bf16 = 4 VGPR
typedef __attribute__((ext_vector_type(4))) float floatx4;   // MFMA C/D

// workspace byte offsets (R21/R22 layout)
constexpr int OFF_CW  = 0;
constexpr int OFF_CB  = 262144;
constexpr int OFF_BT  = 264192;
constexpr int OFF_BU  = 265216;
constexpr int OFF_MTH = 266240;
constexpr int OFF_MTL = 659456;
constexpr int OFF_MUH = 1052672;
constexpr int OFF_MUL = 1183744;
constexpr int OFF_GW4 = 1314816;  // fallback only
constexpr int OFF_FW4 = 1576960;  // fallback only
constexpr int OFF_MT4 = 1839104;
constexpr int OFF_MU4 = 2625536;
constexpr int OFF_GTH = 2887680;
constexpr int OFF_GUH = 3280896;
constexpr int OFF_GB2 = 3411968;
constexpr int OFF_FFH = 3412992;
constexpr int OFF_FFL = 3544064;
constexpr long OFF_F  = 3675136;  // f32 F [65536][256]; H overlays F
constexpr long WS_NEED = OFF_F + 67108864L;

__device__ inline unsigned short f2b(float f) {
  __hip_bfloat16 h = __float2bfloat16(f);
  return __builtin_bit_cast(unsigned short, h);
}
__device__ inline float b2f(unsigned short u) {
  unsigned int v = ((unsigned int)u) << 16;
  return __builtin_bit_cast(float, v);
}
__device__ inline void split2(float v, unsigned short& h, unsigned short& l) {
  h = f2b(v);
  l = f2b(v - b2f(h));
}

// ---------------- precompute (tiny, L2-resident; validated) ----------------

__global__ void k_combine(const float* __restrict__ ipw, const float* __restrict__ opw,
                          char* __restrict__ wsb) {
  float* cw = (float*)(wsb + OFF_CW);
  int n = blockIdx.x * 256 + threadIdx.x;
  int i = n >> 14, o = (n >> 7) & 127, d = n & 127;
  const float* op = opw + i * 16384 + o * 128;
  const float* iv = ipw + i * 49152 + 256 * 128 + d;
  float s = 0.f;
#pragma unroll 4
  for (int m = 0; m < 128; ++m) s = fmaf(op[m], iv[m * 128], s);
  cw[i * 16384 + d * 128 + o] = s;
}

__global__ void k_combine_bias(const float* __restrict__ ipb, const float* __restrict__ opb,
                               const float* __restrict__ opw, char* __restrict__ wsb) {
  float* cb = (float*)(wsb + OFF_CB);
  int t = blockIdx.x * 256 + threadIdx.x;
  int i = t >> 7, o = t & 127;
  const float* op = opw + i * 16384 + o * 128;
  const float* ib = ipb + i * 384 + 256;
  float s = opb[i * 128 + o];
#pragma unroll 4
  for (int m = 0; m < 128; ++m) s = fmaf(op[m], ib[m], s);
  cb[t] = s;
}

__global__ void k_mt_hl(const float* __restrict__ tm_w, char* __restrict__ wsb) {
  const float* cw = (const float*)(wsb + OFF_CW);
  unsigned short* dh = (unsigned short*)(wsb + OFF_MTH);
  unsigned short* dl = (unsigned short*)(wsb + OFF_MTL);
  int n = blockIdx.x * 256 + threadIdx.x;
  int k = n >> 8, c = n & 255;
  const float* p = cw + ((c >> 7) ? 3 : 0) * 16384 + (c & 127);
  float s = 0.f;
#pragma unroll 4
  for (int d = 0; d < 128; ++d) s = fmaf(p[d * 128], tm_w[d * 768 + k], s);
  unsigned short h, l;
  split2(s, h, l);
  int ofs = (((k >> 3) * 256 + c) << 3) + (k & 7);
  dh[ofs] = h;
  dl[ofs] = l;
}

__global__ void k_mu_hl(const float* __restrict__ um_w, char* __restrict__ wsb) {
  const float* cw = (const float*)(wsb + OFF_CW);
  unsigned short* dh = (unsigned short*)(wsb + OFF_MUH);
  unsigned short* dl = (unsigned short*)(wsb + OFF_MUL);
  int n = blockIdx.x * 256 + threadIdx.x;
  int k = n >> 8, c = n & 255;
  const float* p = cw + ((c >> 7) ? 1 : 2) * 16384 + (c & 127);
  float s = 0.f;
#pragma unroll 4
  for (int d = 0; d < 128; ++d) s = fmaf(p[d * 128], um_w[d * 256 + k], s);
  unsigned short h, l;
  split2(s, h, l);
  int ofs = (((k >> 3) * 256 + c) << 3) + (k & 7);
  dh[ofs] = h;
  dl[ofs] = l;
}

__global__ void k_ff_hl(const float* __restrict__ ff_w, char* __restrict__ wsb) {
  unsigned short* dh = (unsigned short*)(wsb + OFF_FFH);
  unsigned short* dl = (unsigned short*)(wsb + OFF_FFL);
  int idx = blockIdx.x * 256 + threadIdx.x;
  int k = idx >> 8, n = idx & 255;
  unsigned short h, l;
  split2(ff_w[n * 256 + k], h, l);
  int ofs = (((k >> 3) * 256 + n) << 3) + (k & 7);
  dh[ofs] = h;
  dl[ofs] = l;
}

__global__ void k_mt4(const float* __restrict__ tm_w, char* __restrict__ wsb) {
  const float* cw = (const float*)(wsb + OFF_CW);
  float* dst = (float*)(wsb + OFF_MT4);
  int n = blockIdx.x * 256 + threadIdx.x;
  int k = n >> 8, c = n & 255;
  const float* p = cw + ((c >> 7) ? 3 : 0) * 16384 + (c & 127);
  float s = 0.f;
#pragma unroll 4
  for (int d = 0; d < 128; ++d) s = fmaf(p[d * 128], tm_w[d * 768 + k], s);
  dst[(((k >> 2) * 256 + c) << 2) + (k & 3)] = s;
}

__global__ void k_mu4(const float* __restrict__ um_w, char* __restrict__ wsb) {
  const float* cw = (const float*)(wsb + OFF_CW);
  float* dst = (float*)(wsb + OFF_MU4);
  int n = blockIdx.x * 256 + threadIdx.x;
  int k = n >> 8, c = n & 255;
  const float* p = cw + ((c >> 7) ? 1 : 2) * 16384 + (c & 127);
  float s = 0.f;
#pragma unroll 4
  for (int d = 0; d < 128; ++d) s = fmaf(p[d * 128], um_w[d * 256 + k], s);
  dst[(((k >> 2) * 256 + c) << 2) + (k & 3)] = s;
}

__global__ void k_bias_tu(const float* __restrict__ tm_b, const float* __restrict__ um_b,
                          char* __restrict__ wsb) {
  const float* cw = (const float*)(wsb + OFF_CW);
  const float* cb = (const float*)(wsb + OFF_CB);
  float* bT = (float*)(wsb + OFF_BT);
  float* bU = (float*)(wsb + OFF_BU);
  int t = blockIdx.x * 256 + threadIdx.x;
  if (t < 256) {
    int sel = (t >> 7) ? 3 : 0;
    const float* p = cw + sel * 16384 + (t & 127);
    float s = cb[sel * 128 + (t & 127)];
#pragma unroll 4
    for (int d = 0; d < 128; ++d) s = fmaf(p[d * 128], tm_b[d], s);
    bT[t] = s;
  } else {
    int c = t - 256;
    int sel = (c >> 7) ? 1 : 2;
    const float* p = cw + sel * 16384 + (c & 127);
    float s = cb[sel * 128 + (c & 127)];
#pragma unroll 4
    for (int d = 0; d < 128; ++d) s = fmaf(p[d * 128], um_b[d], s);
    bU[c] = s;
  }
}

__global__ void k_gt(const float* __restrict__ tg_w, const float* __restrict__ ug_w,
                     char* __restrict__ wsb) {
  const float* mt = (const float*)(wsb + OFF_MT4);
  unsigned short* dst = (unsigned short*)(wsb + OFF_GTH);
  int idx = blockIdx.x * 256 + threadIdx.x;
  int k = idx >> 8, n = idx & 255;
  const float* mb = mt + (((k >> 2) * 256) << 2) + (k & 3);
  float s = 0.f;
  if (n < 128) {
    const float* w = tg_w + n * 256;
#pragma unroll 4
    for (int m = 0; m < 128; ++m) s = fmaf(w[m], mb[m * 4], s);
  } else {
    const float* w = ug_w + (n - 128) * 256 + 128;
#pragma unroll 4
    for (int m = 0; m < 128; ++m) s = fmaf(w[m], mb[(128 + m) * 4], s);
  }
  dst[(((k >> 3) * 256 + n) << 3) + (k & 7)] = f2b(s);
}

__global__ void k_gu(const float* __restrict__ tg_w, const float* __restrict__ ug_w,
                     char* __restrict__ wsb) {
  const float* mu = (const float*)(wsb + OFF_MU4);
  unsigned short* dst = (unsigned short*)(wsb + OFF_GUH);
  int idx = blockIdx.x * 256 + threadIdx.x;
  int k = idx >> 8, n = idx & 255;
  const float* mb = mu + (((k >> 2) * 256) << 2) + (k & 3);
  float s = 0.f;
  if (n < 128) {
    const float* w = tg_w + n * 256 + 128;
#pragma unroll 4
    for (int m = 0; m < 128; ++m) s = fmaf(w[m], mb[m * 4], s);
  } else {
    const float* w = ug_w + (n - 128) * 256;
#pragma unroll 4
    for (int m = 0; m < 128; ++m) s = fmaf(w[m], mb[(128 + m) * 4], s);
  }
  dst[(((k >> 3) * 256 + n) << 3) + (k & 7)] = f2b(s);
}

__global__ void k_gbias(const float* __restrict__ tg_w, const float* __restrict__ tg_b,
                        const float* __restrict__ ug_w, const float* __restrict__ ug_b,
                        char* __restrict__ wsb) {
  const float* bT = (const float*)(wsb + OFF_BT);
  const float* bU = (const float*)(wsb + OFF_BU);
  float* gb2 = (float*)(wsb + OFF_GB2);
  int n = threadIdx.x;
  float s;
  if (n < 128) {
    s = tg_b[n];
    const float* w = tg_w + n * 256;
#pragma unroll 4
    for (int m = 0; m < 128; ++m) s = fmaf(w[m], bT[m], s);
#pragma unroll 4
    for (int m = 0; m < 128; ++m) s = fmaf(w[128 + m], bU[m], s);
  } else {
    int np = n - 128;
    s = ug_b[np];
    const float* w = ug_w + np * 256;
#pragma unroll 4
    for (int m = 0; m < 128; ++m) s = fmaf(w[m], bU[128 + m], s);
#pragma unroll 4
    for (int m = 0; m < 128; ++m) s = fmaf(w[128 + m], bT[128 + m], s);
  }
  gb2[n] = s;
}

__global__ void k_pack_gw4(const float* __restrict__ tg_w, const float* __restrict__ ug_w,
                           char* __restrict__ wsb) {
  float* dst = (float*)(wsb + OFF_GW4);
  int idx = blockIdx.x * 256 + threadIdx.x;
  int j = idx >> 8, n = idx & 255;
  float v = (n < 128) ? tg_w[n * 256 + j] : ug_w[(n - 128) * 256 + j];
  dst[(((j >> 2) * 256 + n) << 2) + (j & 3)] = v;
}

__global__ void k_transpose4(const float* __restrict__ src, float* __restrict__ dst,
                             int R, int C) {
  int n = blockIdx.x * 256 + threadIdx.x;
  if (n >= R * C) return;
  int o = n / C, k = n % C;
  dst[(((k >> 2) * R + o) << 2) + (k & 3)] = src[n];
}

// ---------------- kA: MFMA stages 1/2 + folded gates -> F global ----------------
// R22 structure (4 K-passes, 32 KB LDS) + T14 register prefetch.

#define SWZ(byte, row) ((byte) ^ (((row) & 7) << 4))

__launch_bounds__(512)
__global__ void k_s12g(const float* __restrict__ xt_g, const float* __restrict__ xu_g,
                       const char* __restrict__ wsb, float* __restrict__ Fg) {
  __shared__ __align__(16) char sm[32768];
  constexpr int XTL = 12288;   // xt lo  (xt hi at 0; [32][192] bf16 = 12288 B each)
  constexpr int XUH = 24576;   // xu hi  ([32][64] bf16 = 4096 B each)
  constexpr int XUL = 28672;   // xu lo

  const int t = threadIdx.x;
  const int wave = t >> 6, lane = t & 63;
  const int lrow = lane & 15;
  const int lk8 = lane >> 4;
  const int n0w = wave * 32;
  const long row0 = (long)blockIdx.x * 32;

  const float* bT = (const float*)(wsb + OFF_BT);
  const float* bU = (const float*)(wsb + OFF_BU);
  const float* gb2 = (const float*)(wsb + OFF_GB2);

  // per-thread staging coords (pass-independent)
  int xtrow[3], xtrem[3];
#pragma unroll
  for (int it = 0; it < 3; ++it) {
    int idx = it * 512 + t;
    xtrow[it] = idx / 48;
    xtrem[it] = idx - xtrow[it] * 48;
  }
  const int xurow = t >> 4, xurem = t & 15;

  floatx4 zero = {0.f, 0.f, 0.f, 0.f};
  floatx4 acc1[2][2] = {{zero, zero}, {zero, zero}};
  floatx4 acc2[2][2] = {{zero, zero}, {zero, zero}};
  floatx4 accG1[2][2] = {{zero, zero}, {zero, zero}};
  floatx4 accG2[2][2] = {{zero, zero}, {zero, zero}};

  float4 cur[4], nxt[4];
  // prologue: load pass 0
#pragma unroll
  for (int it = 0; it < 3; ++it)
    cur[it] = *(const float4*)(xt_g + (row0 + xtrow[it]) * 768 + 0 * 192 + xtrem[it] * 4);
  cur[3] = *(const float4*)(xu_g + (row0 + xurow) * 256 + 0 * 64 + xurem * 4);

#pragma unroll
  for (int p = 0; p < 4; ++p) {
    if (p) __syncthreads();  // prior pass's LDS reads complete before overwrite

    // ---- write staged regs -> LDS hi/lo ----
#pragma unroll
    for (int it = 0; it < 3; ++it) {
      int b0 = xtrow[it] * 384 + xtrem[it] * 8;
      ushort4 hh, ll;
      split2(cur[it].x, hh.x, ll.x); split2(cur[it].y, hh.y, ll.y);
      split2(cur[it].z, hh.z, ll.z); split2(cur[it].w, hh.w, ll.w);
      *(ushort4*)(sm + SWZ(b0, xtrow[it])) = hh;
      *(ushort4*)(sm + XTL + SWZ(b0, xtrow[it])) = ll;
    }
    {
      int b0 = xurow * 128 + xurem * 8;
      ushort4 hh, ll;
      split2(cur[3].x, hh.x, ll.x); split2(cur[3].y, hh.y, ll.y);
      split2(cur[3].z, hh.z, ll.z); split2(cur[3].w, hh.w, ll.w);
      *(ushort4*)(sm + XUH + SWZ(b0, xurow)) = hh;
      *(ushort4*)(sm + XUL + SWZ(b0, xurow)) = ll;
    }

    // ---- T14: issue NEXT pass's loads (latency hides under MFMA below) ----
    if (p < 3) {
#pragma unroll
      for (int it = 0; it < 3; ++it)
        nxt[it] = *(const float4*)(xt_g + (row0 + xtrow[it]) * 768 + (p + 1) * 192 + xtrem[it] * 4);
      nxt[3] = *(const float4*)(xu_g + (row0 + xurow) * 256 + (p + 1) * 64 + xurem * 4);
    }
    __syncthreads();

    // ---- stage 1 MFMA over this K-window (6 chunks of 32) ----
    {
      const char* wh = wsb + OFF_MTH;
      const char* wl = wsb + OFF_MTL;
      const char* gt = wsb + OFF_GTH;
#pragma unroll
      for (int kk = 0; kk < 192; kk += 32) {
        int kb = (kk + lk8 * 8) * 2;
        int k8 = ((p * 192 + kk) >> 3) + lk8;
        int o0 = (k8 * 256 + n0w + lrow) << 4;
        int o1 = (k8 * 256 + n0w + 16 + lrow) << 4;
        short8v bh0 = *(const short8v*)(wh + o0);
        short8v bh1 = *(const short8v*)(wh + o1);
        short8v bl0 = *(const short8v*)(wl + o0);
        short8v bl1 = *(const short8v*)(wl + o1);
        short8v g0 = *(const short8v*)(gt + o0);
        short8v g1 = *(const short8v*)(gt + o1);
#pragma unroll
        for (int rg = 0; rg < 2; ++rg) {
          int ar = rg * 16 + lrow;
          short8v ah = *(const short8v*)(sm + SWZ(ar * 384 + kb, ar));
          short8v al = *(const short8v*)(sm + XTL + SWZ(ar * 384 + kb, ar));
          acc1[rg][0] = __builtin_amdgcn_mfma_f32_16x16x32_bf16(ah, bh0, acc1[rg][0], 0, 0, 0);
          acc1[rg][0] = __builtin_amdgcn_mfma_f32_16x16x32_bf16(ah, bl0, acc1[rg][0], 0, 0, 0);
          acc1[rg][0] = __builtin_amdgcn_mfma_f32_16x16x32_bf16(al, bh0, acc1[rg][0], 0, 0, 0);
          acc1[rg][1] = __builtin_amdgcn_mfma_f32_16x16x32_bf16(ah, bh1, acc1[rg][1], 0, 0, 0);
          acc1[rg][1] = __builtin_amdgcn_mfma_f32_16x16x32_bf16(ah, bl1, acc1[rg][1], 0, 0, 0);
          acc1[rg][1] = __builtin_amdgcn_mfma_f32_16x16x32_bf16(al, bh1, acc1[rg][1], 0, 0, 0);
          accG1[rg][0] = __builtin_amdgcn_mfma_f32_16x16x32_bf16(ah, g0, accG1[rg][0], 0, 0, 0);
          accG1[rg][1] = __builtin_amdgcn_mfma_f32_16x16x32_bf16(ah, g1, accG1[rg][1], 0, 0, 0);
        }
      }
    }
    // ---- stage 2 MFMA over this K-window (2 chunks of 32) ----
    {
      const char* wh = wsb + OFF_MUH;
      const char* wl = wsb + OFF_MUL;
      const char* gu = wsb + OFF_GUH;
#pragma unroll
      for (int kk = 0; kk < 64; kk += 32) {
        int kb = (kk + lk8 * 8) * 2;
        int k8 = ((p * 64 + kk) >> 3) + lk8;
        int o0 = (k8 * 256 + n0w + lrow) << 4;
        int o1 = (k8 * 256 + n0w + 16 + lrow) << 4;
        short8v bh0 = *(const short8v*)(wh + o0);
        short8v bh1 = *(const short8v*)(wh + o1);
        short8v bl0 = *(const short8v*)(wl + o0);
        short8v bl1 = *(const short8v*)(wl + o1);
        short8v g0 = *(const short8v*)(gu + o0);
        short8v g1 = *(const short8v*)(gu + o1);
#pragma unroll
        for (int rg = 0; rg < 2; ++rg) {
          int ar = rg * 16 + lrow;
          short8v ah = *(const short8v*)(sm + XUH + SWZ(ar * 128 + kb, ar));
          short8v al = *(const short8v*)(sm + XUL + SWZ(ar * 128 + kb, ar));
          acc2[rg][0] = __builtin_amdgcn_mfma_f32_16x16x32_bf16(ah, bh0, acc2[rg][0], 0, 0, 0);
          acc2[rg][0] = __builtin_amdgcn_mfma_f32_16x16x32_bf16(ah, bl0, acc2[rg][0], 0, 0, 0);
          acc2[rg][0] = __builtin_amdgcn_mfma_f32_16x16x32_bf16(al, bh0, acc2[rg][0], 0, 0, 0);
          acc2[rg][1] = __builtin_amdgcn_mfma_f32_16x16x32_bf16(ah, bh1, acc2[rg][1], 0, 0, 0);
          acc2[rg][1] = __builtin_amdgcn_mfma_f32_16x16x32_bf16(ah, bl1, acc2[rg][1], 0, 0, 0);
          acc2[rg][1] = __builtin_amdgcn_mfma_f32_16x16x32_bf16(al, bh1, acc2[rg][1], 0, 0, 0);
          accG2[rg][0] = __builtin_amdgcn_mfma_f32_16x16x32_bf16(ah, g0, accG2[rg][0], 0, 0, 0);
          accG2[rg][1] = __builtin_amdgcn_mfma_f32_16x16x32_bf16(ah, g1, accG2[rg][1], 0, 0, 0);
        }
      }
    }

    if (p < 3) {
#pragma unroll
      for (int i = 0; i < 4; ++i) cur[i] = nxt[i];
    }
  }

  // ---- epilogue: sigmoid + mix -> F global (R20-validated, quarantine-compliant) ----
#pragma unroll
  for (int rg = 0; rg < 2; ++rg)
#pragma unroll
    for (int nt = 0; nt < 2; ++nt) {
      int n = n0w + nt * 16 + lrow;
      float bvT = bT[n], bvU = bU[n], gbn = gb2[n];
#pragma unroll
      for (int reg = 0; reg < 4; ++reg) {
        long row = row0 + rg * 16 + lk8 * 4 + reg;
        float a1 = acc1[rg][nt][reg] + bvT;
        float a2 = acc2[rg][nt][reg] + bvU;
        float logit = accG1[rg][nt][reg] + accG2[rg][nt][reg] + gbn;
        float g = 1.f / (1.f + __expf(-logit));
        float f = (n < 128) ? fmaf(g, a2 - a1, a1)
                            : fmaf(g, a1 - a2, a2);
        Fg[row * 256 + n] = f;
      }
    }
}

// ---------------- kB1: ff MFMA (R21-verbatim; H over F) ----------------

__launch_bounds__(512)
__global__ void k_ff32(float* FHg, const char* __restrict__ wsb,
                       const float* __restrict__ ff_b) {
  __shared__ __align__(16) char sm[32768];
  constexpr int FLO = 16384;

  const int t = threadIdx.x;
  const int wave = t >> 6, lane = t & 63;
  const int lrow = lane & 15;
  const int lk8 = lane >> 4;
  const int n0w = wave * 32;
  const long row0 = (long)blockIdx.x * 32;

#pragma unroll
  for (int it = 0; it < 4; ++it) {
    int idx = it * 512 + t;
    int row = idx >> 6, rem = idx & 63;
    float4 v = *(const float4*)(FHg + (row0 + row) * 256 + rem * 4);
    int b0 = row * 512 + rem * 8;
    ushort4 hh, ll;
    split2(v.x, hh.x, ll.x); split2(v.y, hh.y, ll.y);
    split2(v.z, hh.z, ll.z); split2(v.w, hh.w, ll.w);
    *(ushort4*)(sm + SWZ(b0, row)) = hh;
    *(ushort4*)(sm + FLO + SWZ(b0, row)) = ll;
  }
  __syncthreads();

  floatx4 zero = {0.f, 0.f, 0.f, 0.f};
  floatx4 acc[2][2] = {{zero, zero}, {zero, zero}};

  {
    const char* wh = wsb + OFF_FFH;
    const char* wl = wsb + OFF_FFL;
#pragma unroll
    for (int kk = 0; kk < 256; kk += 32) {
      int kb = (kk + lk8 * 8) * 2;
      int k8 = (kk >> 3) + lk8;
      int o0 = (k8 * 256 + n0w + lrow) << 4;
      int o1 = (k8 * 256 + n0w + 16 + lrow) << 4;
      short8v bh0 = *(const short8v*)(wh + o0);
      short8v bh1 = *(const short8v*)(wh + o1);
      short8v bl0 = *(const short8v*)(wl + o0);
      short8v bl1 = *(const short8v*)(wl + o1);
#pragma unroll
      for (int rg = 0; rg < 2; ++rg) {
        int ar = rg * 16 + lrow;
        short8v ah = *(const short8v*)(sm + SWZ(ar * 512 + kb, ar));
        short8v al = *(const short8v*)(sm + FLO + SWZ(ar * 512 + kb, ar));
        acc[rg][0] = __builtin_amdgcn_mfma_f32_16x16x32_bf16(ah, bh0, acc[rg][0], 0, 0, 0);
        acc[rg][0] = __builtin_amdgcn_mfma_f32_16x16x32_bf16(ah, bl0, acc[rg][0], 0, 0, 0);
        acc[rg][0] = __builtin_amdgcn_mfma_f32_16x16x32_bf16(al, bh0, acc[rg][0], 0, 0, 0);
        acc[rg][1] = __builtin_amdgcn_mfma_f32_16x16x32_bf16(ah, bh1, acc[rg][1], 0, 0, 0);
        acc[rg][1] = __builtin_amdgcn_mfma_f32_16x16x32_bf16(ah, bl1, acc[rg][1], 0, 0, 0);
        acc[rg][1] = __builtin_amdgcn_mfma_f32_16x16x32_bf16(al, bh1, acc[rg][1], 0, 0, 0);
      }
    }
  }

#pragma unroll
  for (int rg = 0; rg < 2; ++rg)
#pragma unroll
    for (int nt = 0; nt < 2; ++nt) {
      int n = n0w + nt * 16 + lrow;
      float fb = ff_b[n];
#pragma unroll
      for (int reg = 0; reg < 4; ++reg) {
        long row = row0 + rg * 16 + lk8 * 4 + reg;
        FHg[row * 256 + n] = acc[rg][nt][reg] + fb;
      }
    }
}

// ---------------- kB2: LayerNorm + ReLU (R21-verbatim) ----------------

__launch_bounds__(256)
__global__ void k_ln(const float* __restrict__ Hg, const float* __restrict__ ln_g,
                     const float* __restrict__ ln_b, float* __restrict__ out) {
  const int t = threadIdx.x;
  const long row0 = (long)blockIdx.x * 16;
  int r = t >> 4, q = t & 15;
  const float* Hr = Hg + (row0 + r) * 256 + q * 16;
  float4 hv[4];
  float s1 = 0.f, s2 = 0.f;
#pragma unroll
  for (int j = 0; j < 4; ++j) {
    hv[j] = *(const float4*)(Hr + j * 4);
    s1 += hv[j].x + hv[j].y + hv[j].z + hv[j].w;
    s2 += hv[j].x * hv[j].x + hv[j].y * hv[j].y + hv[j].z * hv[j].z + hv[j].w * hv[j].w;
  }
#pragma unroll
  for (int off = 1; off < 16; off <<= 1) {
    s1 += __shfl_xor(s1, off);
    s2 += __shfl_xor(s2, off);
  }
  float mu = s1 * (1.f / 256.f);
  float var = s2 * (1.f / 256.f) - mu * mu;
  float rstd = rsqrtf(var + 1e-5f);
  float* op = out + (row0 + r) * 256 + q * 16;
#pragma unroll
  for (int j = 0; j < 4; ++j) {
    const float* gp = ln_g + q * 16 + j * 4;
    const float* bp = ln_b + q * 16 + j * 4;
    float4 o;
    o.x = fmaf((hv[j].x - mu) * rstd, gp[0], bp[0]);
    o.y = fmaf((hv[j].y - mu) * rstd, gp[1], bp[1]);
    o.z = fmaf((hv[j].z - mu) * rstd, gp[2], bp[2]);
    o.w = fmaf((hv[j].w - mu) * rstd, gp[3], bp[3]);
    o.x = o.x > 0.f ? o.x : 0.f;
    o.y = o.y > 0.f ? o.y : 0.f;
    o.z = o.z > 0.f ? o.z : 0.f;
    o.w = o.w > 0.f ? o.w : 0.f;
    *(float4*)(op + j * 4) = o;
  }
}

// ---------------- fallback: R5 fused scalar kernel (known-pass) ----------------

__launch_bounds__(256)
__global__ void k_main5(const float* __restrict__ xt_g, const float* __restrict__ xu_g,
                        const char* __restrict__ wsb,
                        const float* __restrict__ tg_b, const float* __restrict__ ug_b,
                        const float* __restrict__ ff_b, const float* __restrict__ ln_g,
                        const float* __restrict__ ln_b, float* __restrict__ out) {
  __shared__ float lds[8 * 768 + 8 * 512 + 8 * 256];  // 48 KB
  float* xt = lds;
  float* S = lds + 8 * 768;
  float* xu = lds + 8 * 768 + 8 * 512;

  const int t = threadIdx.x;
  const long row0 = (long)blockIdx.x * 8;

  {
    const float4* g = (const float4*)(xt_g + row0 * 768);
    float4* l = (float4*)xt;
#pragma unroll
    for (int it = 0; it < 6; ++it) l[it * 256 + t] = g[it * 256 + t];
    const float4* gu = (const float4*)(xu_g + row0 * 256);
    float4* lu = (float4*)xu;
#pragma unroll
    for (int it = 0; it < 2; ++it) lu[it * 256 + t] = gu[it * 256 + t];
  }
  __syncthreads();

  {
    const float4* W4 = (const float4*)(wsb + OFF_MT4);
    float acc[8];
#pragma unroll
    for (int r = 0; r < 8; ++r) acc[r] = 0.f;
    for (int k = 0; k < 768; k += 4) {
      float4 w = W4[(k >> 2) * 256 + t];
#pragma unroll
      for (int r = 0; r < 8; ++r) {
        float4 xv = *(const float4*)&xt[r * 768 + k];
        acc[r] = fmaf(w.x, xv.x, acc[r]);
        acc[r] = fmaf(w.y, xv.y, acc[r]);
        acc[r] = fmaf(w.z, xv.z, acc[r]);
        acc[r] = fmaf(w.w, xv.w, acc[r]);
      }
    }
    float bias = ((const float*)(wsb + OFF_BT))[t];
    int d = (t < 128) ? t : (256 + t);
#pragma unroll
    for (int r = 0; r < 8; ++r) S[r * 512 + d] = acc[r] + bias;
  }

  {
    const float4* W4 = (const float4*)(wsb + OFF_MU4);
    float acc[8];
#pragma unroll
    for (int r = 0; r < 8; ++r) acc[r] = 0.f;
    for (int k = 0; k < 256; k += 4) {
      float4 w = W4[(k >> 2) * 256 + t];
#pragma unroll
      for (int r = 0; r < 8; ++r) {
        float4 xv = *(const float4*)&xu[r * 256 + k];
        acc[r] = fmaf(w.x, xv.x, acc[r]);
        acc[r] = fmaf(w.y, xv.y, acc[r]);
        acc[r] = fmaf(w.z, xv.z, acc[r]);
        acc[r] = fmaf(w.w, xv.w, acc[r]);
      }
    }
    float bias = ((const float*)(wsb + OFF_BU))[t];
#pragma unroll
    for (int r = 0; r < 8; ++r) S[r * 512 + 128 + t] = acc[r] + bias;
  }
  __syncthreads();

  {
    int c = t & 127, half = t >> 7;
    const float4* W4 = (const float4*)(wsb + OFF_GW4);
    const int wcol = half * 128 + c;
    const int so = half * 256;
    float acc[8];
#pragma unroll
    for (int r = 0; r < 8; ++r) acc[r] = 0.f;
    for (int j = 0; j < 256; j += 4) {
      float4 w = W4[(j >> 2) * 256 + wcol];
#pragma unroll
      for (int r = 0; r < 8; ++r) {
        float4 sv = *(const float4*)&S[r * 512 + so + j];
        acc[r] = fmaf(w.x, sv.x, acc[r]);
        acc[r] = fmaf(w.y, sv.y, acc[r]);
        acc[r] = fmaf(w.z, sv.z, acc[r]);
        acc[r] = fmaf(w.w, sv.w, acc[r]);
      }
    }
    float gb = half ? ug_b[c] : tg_b[c];
    float* F = xu;
#pragma unroll
    for (int r = 0; r < 8; ++r) {
      float g = 1.f / (1.f + __expf(-(acc[r] + gb)));
      float a = S[r * 512 + so + c];
      float b = S[r * 512 + so + 128 + c];
      F[r * 256 + half * 128 + c] = fmaf(g, b - a, a);
    }
  }
  __syncthreads();

  {
    const float4* W4 = (const float4*)(wsb + OFF_FW4);
    const float* F = xu;
    float acc[8];
#pragma unroll
    for (int r = 0; r < 8; ++r) acc[r] = 0.f;
    for (int j = 0; j < 256; j += 4) {
      float4 w = W4[(j >> 2) * 256 + t];
#pragma unroll
      for (int r = 0; r < 8; ++r) {
        float4 fv = *(const float4*)&F[r * 256 + j];
        acc[r] = fmaf(w.x, fv.x, acc[r]);
        acc[r] = fmaf(w.y, fv.y, acc[r]);
        acc[r] = fmaf(w.z, fv.z, acc[r]);
        acc[r] = fmaf(w.w, fv.w, acc[r]);
      }
    }
    float* H = xt;
    float bias = ff_b[t];
#pragma unroll
    for (int r = 0; r < 8; ++r) H[r * 256 + t] = acc[r] + bias;
  }
  __syncthreads();

  {
    const float* H = xt;
    int r = t >> 5, q = t & 31;
    const float* Hr = H + r * 256 + q * 8;
    float s1 = 0.f, s2 = 0.f;
#pragma unroll
    for (int i = 0; i < 8; ++i) {
      float v = Hr[i];
      s1 += v;
      s2 += v * v;
    }
#pragma unroll
    for (int off = 1; off < 32; off <<= 1) {
      s1 += __shfl_xor(s1, off);
      s2 += __shfl_xor(s2, off);
    }
    float mu = s1 * (1.f / 256.f);
    float var = s2 * (1.f / 256.f) - mu * mu;
    float rstd = rsqrtf(var + 1e-5f);
    float* op = out + (row0 + r) * 256 + q * 8;
#pragma unroll
    for (int i = 0; i < 8; ++i) {
      float v = (Hr[i] - mu) * rstd * ln_g[q * 8 + i] + ln_b[q * 8 + i];
      op[i] = v > 0.f ? v : 0.f;
    }
  }
}

}  // namespace

extern "C" void kernel_launch(void* const* d_in, const int* in_sizes, int n_in,
                              void* d_out, int out_size, void* d_ws, size_t ws_size,
                              hipStream_t stream) {
  const float* text = (const float*)d_in[0];
  const float* user = (const float*)d_in[1];
  const float* tm_w = (const float*)d_in[2];
  const float* tm_b = (const float*)d_in[3];
  const float* um_w = (const float*)d_in[4];
  const float* um_b = (const float*)d_in[5];
  const float* ipw = (const float*)d_in[6];
  const float* ipb = (const float*)d_in[7];
  const float* opw = (const float*)d_in[8];
  const float* opb = (const float*)d_in[9];
  const float* tg_w = (const float*)d_in[10];
  const float* tg_b = (const float*)d_in[11];
  const float* ug_w = (const float*)d_in[12];
  const float* ug_b = (const float*)d_in[13];
  const float* ff_w = (const float*)d_in[14];
  const float* ff_b = (const float*)d_in[15];
  const float* ln_g = (const float*)d_in[16];
  const float* ln_b = (const float*)d_in[17];
  char* wsb = (char*)d_ws;
  float* out = (float*)d_out;

  // common precompute
  k_combine<<<256, 256, 0, stream>>>(ipw, opw, wsb);
  k_combine_bias<<<2, 256, 0, stream>>>(ipb, opb, opw, wsb);
  k_bias_tu<<<2, 256, 0, stream>>>(tm_b, um_b, wsb);
  k_mt4<<<768, 256, 0, stream>>>(tm_w, wsb);
  k_mu4<<<256, 256, 0, stream>>>(um_w, wsb);

  if ((long)ws_size >= WS_NEED) {
    // fast path: gate-folded MFMA front (prefetched) -> F -> ff MFMA -> LN
    float* Fg = (float*)(wsb + OFF_F);
    k_mt_hl<<<768, 256, 0, stream>>>(tm_w, wsb);
    k_mu_hl<<<256, 256, 0, stream>>>(um_w, wsb);
    k_gt<<<768, 256, 0, stream>>>(tg_w, ug_w, wsb);
    k_gu<<<256, 256, 0, stream>>>(tg_w, ug_w, wsb);
    k_gbias<<<1, 256, 0, stream>>>(tg_w, tg_b, ug_w, ug_b, wsb);
    k_ff_hl<<<256, 256, 0, stream>>>(ff_w, wsb);
    k_s12g<<<2048, 512, 0, stream>>>(text, user, wsb, Fg);
    k_ff32<<<2048, 512, 0, stream>>>(Fg, wsb, ff_b);
    k_ln<<<4096, 256, 0, stream>>>(Fg, ln_g, ln_b, out);
  } else {
    // fallback: R5 fused scalar (known-pass)
    k_pack_gw4<<<256, 256, 0, stream>>>(tg_w, ug_w, wsb);
    k_transpose4<<<256, 256, 0, stream>>>(ff_w, (float*)(wsb + OFF_FW4), 256, 256);
    k_main5<<<8192, 256, 0, stream>>>(text, user, wsb, tg_b, ug_b, ff_b, ln_g, ln_b, out);
  }
}

// Round 24
// 420.524 us; speedup vs baseline: 1.1722x; 1.1722x over previous
//
#include <hip/hip_runtime.h>
#include <hip/hip_bf16.h>

// MultiViewFusion — round 24: REVERT to R21 (validated best: 420us).
// Final evidence ledger:
//   R5 PASS scalar 1338us (algebra: seq_len=1 softmax==1 -> MHA folds to
//     2 linears; whole net = 2 GEMMs + gates + ff + LN).
//   R6-R9 FAIL: MFMA acc->LDS->read corrupts on this toolchain; QUARANTINE:
//     MFMA acc exits only via VALU->global store. Scalar data in LDS fine.
//   R10 self-check: MFMA front coordinate-exact vs scalar reference.
//   R13..R19: two-kernel split ladder 646->539us.
//   R20 500us: gate GEMM+sigmoid+mix folded into kA epilogue (linearity).
//   R21 420us BEST: ff as hi/lo MFMA (k_ff32, H overlays F) + k_ln.
//   R22 (LDS 64->32KB): occupancy UNCHANGED 23% -> not LDS-bound; 437us.
//   R23 (T14 reg prefetch): REGRESSED 493us (waitcnt serialization).
//   => k_s12g's ~280us is structural (2-barrier MFMA schedule @ 2 blocks/CU);
//   R21 composition is the empirical optimum of this design family.

namespace {

typedef __attribute__((ext_vector_type(8))) short short8v;   // 8 bf16 = 4 VGPR
typedef __attribute__((ext_vector_type(4))) float floatx4;   // MFMA C/D

// workspace byte offsets
constexpr int OFF_CW  = 0;
constexpr int OFF_CB  = 262144;
constexpr int OFF_BT  = 264192;
constexpr int OFF_BU  = 265216;
constexpr int OFF_MTH = 266240;
constexpr int OFF_MTL = 659456;
constexpr int OFF_MUH = 1052672;
constexpr int OFF_MUL = 1183744;
constexpr int OFF_GW4 = 1314816;  // fallback only
constexpr int OFF_FW4 = 1576960;  // fallback only
constexpr int OFF_MT4 = 1839104;
constexpr int OFF_MU4 = 2625536;
constexpr int OFF_GTH = 2887680;
constexpr int OFF_GUH = 3280896;
constexpr int OFF_GB2 = 3411968;
constexpr int OFF_FFH = 3412992;
constexpr int OFF_FFL = 3544064;
constexpr long OFF_F  = 3675136;  // f32 F [65536][256] = 67108864 B; H overlays F
constexpr long WS_NEED = OFF_F + 67108864L;

__device__ inline unsigned short f2b(float f) {
  __hip_bfloat16 h = __float2bfloat16(f);
  return __builtin_bit_cast(unsigned short, h);
}
__device__ inline float b2f(unsigned short u) {
  unsigned int v = ((unsigned int)u) << 16;
  return __builtin_bit_cast(float, v);
}
__device__ inline void split2(float v, unsigned short& h, unsigned short& l) {
  h = f2b(v);
  l = f2b(v - b2f(h));
}

// ---------------- precompute (tiny, L2-resident) ----------------

__global__ void k_combine(const float* __restrict__ ipw, const float* __restrict__ opw,
                          char* __restrict__ wsb) {
  float* cw = (float*)(wsb + OFF_CW);
  int n = blockIdx.x * 256 + threadIdx.x;
  int i = n >> 14, o = (n >> 7) & 127, d = n & 127;
  const float* op = opw + i * 16384 + o * 128;
  const float* iv = ipw + i * 49152 + 256 * 128 + d;
  float s = 0.f;
#pragma unroll 4
  for (int m = 0; m < 128; ++m) s = fmaf(op[m], iv[m * 128], s);
  cw[i * 16384 + d * 128 + o] = s;
}

__global__ void k_combine_bias(const float* __restrict__ ipb, const float* __restrict__ opb,
                               const float* __restrict__ opw, char* __restrict__ wsb) {
  float* cb = (float*)(wsb + OFF_CB);
  int t = blockIdx.x * 256 + threadIdx.x;
  int i = t >> 7, o = t & 127;
  const float* op = opw + i * 16384 + o * 128;
  const float* ib = ipb + i * 384 + 256;
  float s = opb[i * 128 + o];
#pragma unroll 4
  for (int m = 0; m < 128; ++m) s = fmaf(op[m], ib[m], s);
  cb[t] = s;
}

__global__ void k_mt_hl(const float* __restrict__ tm_w, char* __restrict__ wsb) {
  const float* cw = (const float*)(wsb + OFF_CW);
  unsigned short* dh = (unsigned short*)(wsb + OFF_MTH);
  unsigned short* dl = (unsigned short*)(wsb + OFF_MTL);
  int n = blockIdx.x * 256 + threadIdx.x;  // 768*256
  int k = n >> 8, c = n & 255;
  const float* p = cw + ((c >> 7) ? 3 : 0) * 16384 + (c & 127);
  float s = 0.f;
#pragma unroll 4
  for (int d = 0; d < 128; ++d) s = fmaf(p[d * 128], tm_w[d * 768 + k], s);
  unsigned short h, l;
  split2(s, h, l);
  int ofs = (((k >> 3) * 256 + c) << 3) + (k & 7);
  dh[ofs] = h;
  dl[ofs] = l;
}

__global__ void k_mu_hl(const float* __restrict__ um_w, char* __restrict__ wsb) {
  const float* cw = (const float*)(wsb + OFF_CW);
  unsigned short* dh = (unsigned short*)(wsb + OFF_MUH);
  unsigned short* dl = (unsigned short*)(wsb + OFF_MUL);
  int n = blockIdx.x * 256 + threadIdx.x;  // 256*256
  int k = n >> 8, c = n & 255;
  const float* p = cw + ((c >> 7) ? 1 : 2) * 16384 + (c & 127);
  float s = 0.f;
#pragma unroll 4
  for (int d = 0; d < 128; ++d) s = fmaf(p[d * 128], um_w[d * 256 + k], s);
  unsigned short h, l;
  split2(s, h, l);
  int ofs = (((k >> 3) * 256 + c) << 3) + (k & 7);
  dh[ofs] = h;
  dl[ofs] = l;
}

// ff hi/lo pack [32][256][8] from ff_w [256][256]
__global__ void k_ff_hl(const float* __restrict__ ff_w, char* __restrict__ wsb) {
  unsigned short* dh = (unsigned short*)(wsb + OFF_FFH);
  unsigned short* dl = (unsigned short*)(wsb + OFF_FFL);
  int idx = blockIdx.x * 256 + threadIdx.x;  // 65536
  int k = idx >> 8, n = idx & 255;
  unsigned short h, l;
  split2(ff_w[n * 256 + k], h, l);
  int ofs = (((k >> 3) * 256 + n) << 3) + (k & 7);
  dh[ofs] = h;
  dl[ofs] = l;
}

// f32 [K/4][256][4] packs
__global__ void k_mt4(const float* __restrict__ tm_w, char* __restrict__ wsb) {
  const float* cw = (const float*)(wsb + OFF_CW);
  float* dst = (float*)(wsb + OFF_MT4);
  int n = blockIdx.x * 256 + threadIdx.x;  // 768*256
  int k = n >> 8, c = n & 255;
  const float* p = cw + ((c >> 7) ? 3 : 0) * 16384 + (c & 127);
  float s = 0.f;
#pragma unroll 4
  for (int d = 0; d < 128; ++d) s = fmaf(p[d * 128], tm_w[d * 768 + k], s);
  dst[(((k >> 2) * 256 + c) << 2) + (k & 3)] = s;
}

__global__ void k_mu4(const float* __restrict__ um_w, char* __restrict__ wsb) {
  const float* cw = (const float*)(wsb + OFF_CW);
  float* dst = (float*)(wsb + OFF_MU4);
  int n = blockIdx.x * 256 + threadIdx.x;  // 256*256
  int k = n >> 8, c = n & 255;
  const float* p = cw + ((c >> 7) ? 1 : 2) * 16384 + (c & 127);
  float s = 0.f;
#pragma unroll 4
  for (int d = 0; d < 128; ++d) s = fmaf(p[d * 128], um_w[d * 256 + k], s);
  dst[(((k >> 2) * 256 + c) << 2) + (k & 3)] = s;
}

__global__ void k_bias_tu(const float* __restrict__ tm_b, const float* __restrict__ um_b,
                          char* __restrict__ wsb) {
  const float* cw = (const float*)(wsb + OFF_CW);
  const float* cb = (const float*)(wsb + OFF_CB);
  float* bT = (float*)(wsb + OFF_BT);
  float* bU = (float*)(wsb + OFF_BU);
  int t = blockIdx.x * 256 + threadIdx.x;
  if (t < 256) {
    int sel = (t >> 7) ? 3 : 0;
    const float* p = cw + sel * 16384 + (t & 127);
    float s = cb[sel * 128 + (t & 127)];
#pragma unroll 4
    for (int d = 0; d < 128; ++d) s = fmaf(p[d * 128], tm_b[d], s);
    bT[t] = s;
  } else {
    int c = t - 256;
    int sel = (c >> 7) ? 1 : 2;
    const float* p = cw + sel * 16384 + (c & 127);
    float s = cb[sel * 128 + (c & 127)];
#pragma unroll 4
    for (int d = 0; d < 128; ++d) s = fmaf(p[d * 128], um_b[d], s);
    bU[c] = s;
  }
}

// Gt[n][k] bf16 hi pack [96][256][8] (R20-validated)
__global__ void k_gt(const float* __restrict__ tg_w, const float* __restrict__ ug_w,
                     char* __restrict__ wsb) {
  const float* mt = (const float*)(wsb + OFF_MT4);
  unsigned short* dst = (unsigned short*)(wsb + OFF_GTH);
  int idx = blockIdx.x * 256 + threadIdx.x;  // 768*256
  int k = idx >> 8, n = idx & 255;
  const float* mb = mt + (((k >> 2) * 256) << 2) + (k & 3);
  float s = 0.f;
  if (n < 128) {
    const float* w = tg_w + n * 256;
#pragma unroll 4
    for (int m = 0; m < 128; ++m) s = fmaf(w[m], mb[m * 4], s);
  } else {
    const float* w = ug_w + (n - 128) * 256 + 128;
#pragma unroll 4
    for (int m = 0; m < 128; ++m) s = fmaf(w[m], mb[(128 + m) * 4], s);
  }
  dst[(((k >> 3) * 256 + n) << 3) + (k & 7)] = f2b(s);
}

// Gu[n][k] bf16 hi pack [32][256][8] (R20-validated)
__global__ void k_gu(const float* __restrict__ tg_w, const float* __restrict__ ug_w,
                     char* __restrict__ wsb) {
  const float* mu = (const float*)(wsb + OFF_MU4);
  unsigned short* dst = (unsigned short*)(wsb + OFF_GUH);
  int idx = blockIdx.x * 256 + threadIdx.x;  // 256*256
  int k = idx >> 8, n = idx & 255;
  const float* mb = mu + (((k >> 2) * 256) << 2) + (k & 3);
  float s = 0.f;
  if (n < 128) {
    const float* w = tg_w + n * 256 + 128;
#pragma unroll 4
    for (int m = 0; m < 128; ++m) s = fmaf(w[m], mb[m * 4], s);
  } else {
    const float* w = ug_w + (n - 128) * 256;
#pragma unroll 4
    for (int m = 0; m < 128; ++m) s = fmaf(w[m], mb[(128 + m) * 4], s);
  }
  dst[(((k >> 3) * 256 + n) << 3) + (k & 7)] = f2b(s);
}

__global__ void k_gbias(const float* __restrict__ tg_w, const float* __restrict__ tg_b,
                        const float* __restrict__ ug_w, const float* __restrict__ ug_b,
                        char* __restrict__ wsb) {
  const float* bT = (const float*)(wsb + OFF_BT);
  const float* bU = (const float*)(wsb + OFF_BU);
  float* gb2 = (float*)(wsb + OFF_GB2);
  int n = threadIdx.x;  // 256
  float s;
  if (n < 128) {
    s = tg_b[n];
    const float* w = tg_w + n * 256;
#pragma unroll 4
    for (int m = 0; m < 128; ++m) s = fmaf(w[m], bT[m], s);
#pragma unroll 4
    for (int m = 0; m < 128; ++m) s = fmaf(w[128 + m], bU[m], s);
  } else {
    int np = n - 128;
    s = ug_b[np];
    const float* w = ug_w + np * 256;
#pragma unroll 4
    for (int m = 0; m < 128; ++m) s = fmaf(w[m], bU[128 + m], s);
#pragma unroll 4
    for (int m = 0; m < 128; ++m) s = fmaf(w[128 + m], bT[128 + m], s);
  }
  gb2[n] = s;
}

// fallback packs
__global__ void k_pack_gw4(const float* __restrict__ tg_w, const float* __restrict__ ug_w,
                           char* __restrict__ wsb) {
  float* dst = (float*)(wsb + OFF_GW4);
  int idx = blockIdx.x * 256 + threadIdx.x;
  int j = idx >> 8, n = idx & 255;
  float v = (n < 128) ? tg_w[n * 256 + j] : ug_w[(n - 128) * 256 + j];
  dst[(((j >> 2) * 256 + n) << 2) + (j & 3)] = v;
}

__global__ void k_transpose4(const float* __restrict__ src, float* __restrict__ dst,
                             int R, int C) {
  int n = blockIdx.x * 256 + threadIdx.x;
  if (n >= R * C) return;
  int o = n / C, k = n % C;
  dst[(((k >> 2) * R + o) << 2) + (k & 3)] = src[n];
}

// ---------------- kA: MFMA stages 1/2 + folded gates -> F global (R20/R21-verbatim) ----------------

#define SWZ(byte, row) ((byte) ^ (((row) & 7) << 4))

__launch_bounds__(512)
__global__ void k_s12g(const float* __restrict__ xt_g, const float* __restrict__ xu_g,
                       const char* __restrict__ wsb, float* __restrict__ Fg) {
  __shared__ __align__(16) char sm[65536];
  constexpr int XTL = 24576;
  constexpr int XUH = 49152;
  constexpr int XUL = 57344;

  const int t = threadIdx.x;
  const int wave = t >> 6, lane = t & 63;
  const int lrow = lane & 15;
  const int lk8 = lane >> 4;
  const int n0w = wave * 32;
  const long row0 = (long)blockIdx.x * 32;

  const float* bT = (const float*)(wsb + OFF_BT);
  const float* bU = (const float*)(wsb + OFF_BU);
  const float* gb2 = (const float*)(wsb + OFF_GB2);

  floatx4 zero = {0.f, 0.f, 0.f, 0.f};
  floatx4 acc1[2][2] = {{zero, zero}, {zero, zero}};
  floatx4 acc2[2][2] = {{zero, zero}, {zero, zero}};
  floatx4 accG1[2][2] = {{zero, zero}, {zero, zero}};
  floatx4 accG2[2][2] = {{zero, zero}, {zero, zero}};

  for (int p = 0; p < 2; ++p) {
    if (p) __syncthreads();

#pragma unroll
    for (int it = 0; it < 6; ++it) {
      int idx = it * 512 + t;
      int row = idx / 96, rem = idx - row * 96;
      float4 v = *(const float4*)(xt_g + (row0 + row) * 768 + p * 384 + rem * 4);
      int b0 = row * 768 + rem * 8;
      ushort4 hh, ll;
      split2(v.x, hh.x, ll.x); split2(v.y, hh.y, ll.y);
      split2(v.z, hh.z, ll.z); split2(v.w, hh.w, ll.w);
      *(ushort4*)(sm + SWZ(b0, row)) = hh;
      *(ushort4*)(sm + XTL + SWZ(b0, row)) = ll;
    }
#pragma unroll
    for (int it = 0; it < 2; ++it) {
      int idx = it * 512 + t;
      int row = idx >> 5, rem = idx & 31;
      float4 v = *(const float4*)(xu_g + (row0 + row) * 256 + p * 128 + rem * 4);
      int b0 = row * 256 + rem * 8;
      ushort4 hh, ll;
      split2(v.x, hh.x, ll.x); split2(v.y, hh.y, ll.y);
      split2(v.z, hh.z, ll.z); split2(v.w, hh.w, ll.w);
      *(ushort4*)(sm + XUH + SWZ(b0, row)) = hh;
      *(ushort4*)(sm + XUL + SWZ(b0, row)) = ll;
    }
    __syncthreads();

    {
      const char* wh = wsb + OFF_MTH;
      const char* wl = wsb + OFF_MTL;
      const char* gt = wsb + OFF_GTH;
#pragma unroll 4
      for (int kk = 0; kk < 384; kk += 32) {
        int kb = (kk + lk8 * 8) * 2;
        int k8 = ((p * 384 + kk) >> 3) + lk8;
        int o0 = (k8 * 256 + n0w + lrow) << 4;
        int o1 = (k8 * 256 + n0w + 16 + lrow) << 4;
        short8v bh0 = *(const short8v*)(wh + o0);
        short8v bh1 = *(const short8v*)(wh + o1);
        short8v bl0 = *(const short8v*)(wl + o0);
        short8v bl1 = *(const short8v*)(wl + o1);
        short8v g0 = *(const short8v*)(gt + o0);
        short8v g1 = *(const short8v*)(gt + o1);
#pragma unroll
        for (int rg = 0; rg < 2; ++rg) {
          int ar = rg * 16 + lrow;
          short8v ah = *(const short8v*)(sm + SWZ(ar * 768 + kb, ar));
          short8v al = *(const short8v*)(sm + XTL + SWZ(ar * 768 + kb, ar));
          acc1[rg][0] = __builtin_amdgcn_mfma_f32_16x16x32_bf16(ah, bh0, acc1[rg][0], 0, 0, 0);
          acc1[rg][0] = __builtin_amdgcn_mfma_f32_16x16x32_bf16(ah, bl0, acc1[rg][0], 0, 0, 0);
          acc1[rg][0] = __builtin_amdgcn_mfma_f32_16x16x32_bf16(al, bh0, acc1[rg][0], 0, 0, 0);
          acc1[rg][1] = __builtin_amdgcn_mfma_f32_16x16x32_bf16(ah, bh1, acc1[rg][1], 0, 0, 0);
          acc1[rg][1] = __builtin_amdgcn_mfma_f32_16x16x32_bf16(ah, bl1, acc1[rg][1], 0, 0, 0);
          acc1[rg][1] = __builtin_amdgcn_mfma_f32_16x16x32_bf16(al, bh1, acc1[rg][1], 0, 0, 0);
          accG1[rg][0] = __builtin_amdgcn_mfma_f32_16x16x32_bf16(ah, g0, accG1[rg][0], 0, 0, 0);
          accG1[rg][1] = __builtin_amdgcn_mfma_f32_16x16x32_bf16(ah, g1, accG1[rg][1], 0, 0, 0);
        }
      }
    }
    {
      const char* wh = wsb + OFF_MUH;
      const char* wl = wsb + OFF_MUL;
      const char* gu = wsb + OFF_GUH;
#pragma unroll
      for (int kk = 0; kk < 128; kk += 32) {
        int kb = (kk + lk8 * 8) * 2;
        int k8 = ((p * 128 + kk) >> 3) + lk8;
        int o0 = (k8 * 256 + n0w + lrow) << 4;
        int o1 = (k8 * 256 + n0w + 16 + lrow) << 4;
        short8v bh0 = *(const short8v*)(wh + o0);
        short8v bh1 = *(const short8v*)(wh + o1);
        short8v bl0 = *(const short8v*)(wl + o0);
        short8v bl1 = *(const short8v*)(wl + o1);
        short8v g0 = *(const short8v*)(gu + o0);
        short8v g1 = *(const short8v*)(gu + o1);
#pragma unroll
        for (int rg = 0; rg < 2; ++rg) {
          int ar = rg * 16 + lrow;
          short8v ah = *(const short8v*)(sm + XUH + SWZ(ar * 256 + kb, ar));
          short8v al = *(const short8v*)(sm + XUL + SWZ(ar * 256 + kb, ar));
          acc2[rg][0] = __builtin_amdgcn_mfma_f32_16x16x32_bf16(ah, bh0, acc2[rg][0], 0, 0, 0);
          acc2[rg][0] = __builtin_amdgcn_mfma_f32_16x16x32_bf16(ah, bl0, acc2[rg][0], 0, 0, 0);
          acc2[rg][0] = __builtin_amdgcn_mfma_f32_16x16x32_bf16(al, bh0, acc2[rg][0], 0, 0, 0);
          acc2[rg][1] = __builtin_amdgcn_mfma_f32_16x16x32_bf16(ah, bh1, acc2[rg][1], 0, 0, 0);
          acc2[rg][1] = __builtin_amdgcn_mfma_f32_16x16x32_bf16(ah, bl1, acc2[rg][1], 0, 0, 0);
          acc2[rg][1] = __builtin_amdgcn_mfma_f32_16x16x32_bf16(al, bh1, acc2[rg][1], 0, 0, 0);
          accG2[rg][0] = __builtin_amdgcn_mfma_f32_16x16x32_bf16(ah, g0, accG2[rg][0], 0, 0, 0);
          accG2[rg][1] = __builtin_amdgcn_mfma_f32_16x16x32_bf16(ah, g1, accG2[rg][1], 0, 0, 0);
        }
      }
    }
  }

  // ---- epilogue: sigmoid + mix -> F global (quarantine-compliant) ----
#pragma unroll
  for (int rg = 0; rg < 2; ++rg)
#pragma unroll
    for (int nt = 0; nt < 2; ++nt) {
      int n = n0w + nt * 16 + lrow;
      float bvT = bT[n], bvU = bU[n], gbn = gb2[n];
#pragma unroll
      for (int reg = 0; reg < 4; ++reg) {
        long row = row0 + rg * 16 + lk8 * 4 + reg;
        float a1 = acc1[rg][nt][reg] + bvT;
        float a2 = acc2[rg][nt][reg] + bvU;
        float logit = accG1[rg][nt][reg] + accG2[rg][nt][reg] + gbn;
        float g = 1.f / (1.f + __expf(-logit));
        float f = (n < 128) ? fmaf(g, a2 - a1, a1)
                            : fmaf(g, a1 - a2, a2);
        Fg[row * 256 + n] = f;
      }
    }
}

// ---------------- kB1: ff MFMA (R21-verbatim; H over F) ----------------

__launch_bounds__(512)
__global__ void k_ff32(float* FHg, const char* __restrict__ wsb,
                       const float* __restrict__ ff_b) {
  __shared__ __align__(16) char sm[32768];
  constexpr int FLO = 16384;

  const int t = threadIdx.x;
  const int wave = t >> 6, lane = t & 63;
  const int lrow = lane & 15;
  const int lk8 = lane >> 4;
  const int n0w = wave * 32;
  const long row0 = (long)blockIdx.x * 32;

#pragma unroll
  for (int it = 0; it < 4; ++it) {
    int idx = it * 512 + t;
    int row = idx >> 6, rem = idx & 63;
    float4 v = *(const float4*)(FHg + (row0 + row) * 256 + rem * 4);
    int b0 = row * 512 + rem * 8;
    ushort4 hh, ll;
    split2(v.x, hh.x, ll.x); split2(v.y, hh.y, ll.y);
    split2(v.z, hh.z, ll.z); split2(v.w, hh.w, ll.w);
    *(ushort4*)(sm + SWZ(b0, row)) = hh;
    *(ushort4*)(sm + FLO + SWZ(b0, row)) = ll;
  }
  __syncthreads();

  floatx4 zero = {0.f, 0.f, 0.f, 0.f};
  floatx4 acc[2][2] = {{zero, zero}, {zero, zero}};

  {
    const char* wh = wsb + OFF_FFH;
    const char* wl = wsb + OFF_FFL;
#pragma unroll
    for (int kk = 0; kk < 256; kk += 32) {
      int kb = (kk + lk8 * 8) * 2;
      int k8 = (kk >> 3) + lk8;
      int o0 = (k8 * 256 + n0w + lrow) << 4;
      int o1 = (k8 * 256 + n0w + 16 + lrow) << 4;
      short8v bh0 = *(const short8v*)(wh + o0);
      short8v bh1 = *(const short8v*)(wh + o1);
      short8v bl0 = *(const short8v*)(wl + o0);
      short8v bl1 = *(const short8v*)(wl + o1);
#pragma unroll
      for (int rg = 0; rg < 2; ++rg) {
        int ar = rg * 16 + lrow;
        short8v ah = *(const short8v*)(sm + SWZ(ar * 512 + kb, ar));
        short8v al = *(const short8v*)(sm + FLO + SWZ(ar * 512 + kb, ar));
        acc[rg][0] = __builtin_amdgcn_mfma_f32_16x16x32_bf16(ah, bh0, acc[rg][0], 0, 0, 0);
        acc[rg][0] = __builtin_amdgcn_mfma_f32_16x16x32_bf16(ah, bl0, acc[rg][0], 0, 0, 0);
        acc[rg][0] = __builtin_amdgcn_mfma_f32_16x16x32_bf16(al, bh0, acc[rg][0], 0, 0, 0);
        acc[rg][1] = __builtin_amdgcn_mfma_f32_16x16x32_bf16(ah, bh1, acc[rg][1], 0, 0, 0);
        acc[rg][1] = __builtin_amdgcn_mfma_f32_16x16x32_bf16(ah, bl1, acc[rg][1], 0, 0, 0);
        acc[rg][1] = __builtin_amdgcn_mfma_f32_16x16x32_bf16(al, bh1, acc[rg][1], 0, 0, 0);
      }
    }
  }

#pragma unroll
  for (int rg = 0; rg < 2; ++rg)
#pragma unroll
    for (int nt = 0; nt < 2; ++nt) {
      int n = n0w + nt * 16 + lrow;
      float fb = ff_b[n];
#pragma unroll
      for (int reg = 0; reg < 4; ++reg) {
        long row = row0 + rg * 16 + lk8 * 4 + reg;
        FHg[row * 256 + n] = acc[rg][nt][reg] + fb;
      }
    }
}

// ---------------- kB2: LayerNorm + ReLU (R21-verbatim) ----------------

__launch_bounds__(256)
__global__ void k_ln(const float* __restrict__ Hg, const float* __restrict__ ln_g,
                     const float* __restrict__ ln_b, float* __restrict__ out) {
  const int t = threadIdx.x;
  const long row0 = (long)blockIdx.x * 16;
  int r = t >> 4, q = t & 15;
  const float* Hr = Hg + (row0 + r) * 256 + q * 16;
  float4 hv[4];
  float s1 = 0.f, s2 = 0.f;
#pragma unroll
  for (int j = 0; j < 4; ++j) {
    hv[j] = *(const float4*)(Hr + j * 4);
    s1 += hv[j].x + hv[j].y + hv[j].z + hv[j].w;
    s2 += hv[j].x * hv[j].x + hv[j].y * hv[j].y + hv[j].z * hv[j].z + hv[j].w * hv[j].w;
  }
#pragma unroll
  for (int off = 1; off < 16; off <<= 1) {
    s1 += __shfl_xor(s1, off);
    s2 += __shfl_xor(s2, off);
  }
  float mu = s1 * (1.f / 256.f);
  float var = s2 * (1.f / 256.f) - mu * mu;
  float rstd = rsqrtf(var + 1e-5f);
  float* op = out + (row0 + r) * 256 + q * 16;
#pragma unroll
  for (int j = 0; j < 4; ++j) {
    const float* gp = ln_g + q * 16 + j * 4;
    const float* bp = ln_b + q * 16 + j * 4;
    float4 o;
    o.x = fmaf((hv[j].x - mu) * rstd, gp[0], bp[0]);
    o.y = fmaf((hv[j].y - mu) * rstd, gp[1], bp[1]);
    o.z = fmaf((hv[j].z - mu) * rstd, gp[2], bp[2]);
    o.w = fmaf((hv[j].w - mu) * rstd, gp[3], bp[3]);
    o.x = o.x > 0.f ? o.x : 0.f;
    o.y = o.y > 0.f ? o.y : 0.f;
    o.z = o.z > 0.f ? o.z : 0.f;
    o.w = o.w > 0.f ? o.w : 0.f;
    *(float4*)(op + j * 4) = o;
  }
}

// ---------------- fallback: R5 fused scalar kernel (known-pass) ----------------

__launch_bounds__(256)
__global__ void k_main5(const float* __restrict__ xt_g, const float* __restrict__ xu_g,
                        const char* __restrict__ wsb,
                        const float* __restrict__ tg_b, const float* __restrict__ ug_b,
                        const float* __restrict__ ff_b, const float* __restrict__ ln_g,
                        const float* __restrict__ ln_b, float* __restrict__ out) {
  __shared__ float lds[8 * 768 + 8 * 512 + 8 * 256];  // 48 KB
  float* xt = lds;
  float* S = lds + 8 * 768;
  float* xu = lds + 8 * 768 + 8 * 512;

  const int t = threadIdx.x;
  const long row0 = (long)blockIdx.x * 8;

  {
    const float4* g = (const float4*)(xt_g + row0 * 768);
    float4* l = (float4*)xt;
#pragma unroll
    for (int it = 0; it < 6; ++it) l[it * 256 + t] = g[it * 256 + t];
    const float4* gu = (const float4*)(xu_g + row0 * 256);
    float4* lu = (float4*)xu;
#pragma unroll
    for (int it = 0; it < 2; ++it) lu[it * 256 + t] = gu[it * 256 + t];
  }
  __syncthreads();

  {
    const float4* W4 = (const float4*)(wsb + OFF_MT4);
    float acc[8];
#pragma unroll
    for (int r = 0; r < 8; ++r) acc[r] = 0.f;
    for (int k = 0; k < 768; k += 4) {
      float4 w = W4[(k >> 2) * 256 + t];
#pragma unroll
      for (int r = 0; r < 8; ++r) {
        float4 xv = *(const float4*)&xt[r * 768 + k];
        acc[r] = fmaf(w.x, xv.x, acc[r]);
        acc[r] = fmaf(w.y, xv.y, acc[r]);
        acc[r] = fmaf(w.z, xv.z, acc[r]);
        acc[r] = fmaf(w.w, xv.w, acc[r]);
      }
    }
    float bias = ((const float*)(wsb + OFF_BT))[t];
    int d = (t < 128) ? t : (256 + t);
#pragma unroll
    for (int r = 0; r < 8; ++r) S[r * 512 + d] = acc[r] + bias;
  }

  {
    const float4* W4 = (const float4*)(wsb + OFF_MU4);
    float acc[8];
#pragma unroll
    for (int r = 0; r < 8; ++r) acc[r] = 0.f;
    for (int k = 0; k < 256; k += 4) {
      float4 w = W4[(k >> 2) * 256 + t];
#pragma unroll
      for (int r = 0; r < 8; ++r) {
        float4 xv = *(const float4*)&xu[r * 256 + k];
        acc[r] = fmaf(w.x, xv.x, acc[r]);
        acc[r] = fmaf(w.y, xv.y, acc[r]);
        acc[r] = fmaf(w.z, xv.z, acc[r]);
        acc[r] = fmaf(w.w, xv.w, acc[r]);
      }
    }
    float bias = ((const float*)(wsb + OFF_BU))[t];
#pragma unroll
    for (int r = 0; r < 8; ++r) S[r * 512 + 128 + t] = acc[r] + bias;
  }
  __syncthreads();

  {
    int c = t & 127, half = t >> 7;
    const float4* W4 = (const float4*)(wsb + OFF_GW4);
    const int wcol = half * 128 + c;
    const int so = half * 256;
    float acc[8];
#pragma unroll
    for (int r = 0; r < 8; ++r) acc[r] = 0.f;
    for (int j = 0; j < 256; j += 4) {
      float4 w = W4[(j >> 2) * 256 + wcol];
#pragma unroll
      for (int r = 0; r < 8; ++r) {
        float4 sv = *(const float4*)&S[r * 512 + so + j];
        acc[r] = fmaf(w.x, sv.x, acc[r]);
        acc[r] = fmaf(w.y, sv.y, acc[r]);
        acc[r] = fmaf(w.z, sv.z, acc[r]);
        acc[r] = fmaf(w.w, sv.w, acc[r]);
      }
    }
    float gb = half ? ug_b[c] : tg_b[c];
    float* F = xu;
#pragma unroll
    for (int r = 0; r < 8; ++r) {
      float g = 1.f / (1.f + __expf(-(acc[r] + gb)));
      float a = S[r * 512 + so + c];
      float b = S[r * 512 + so + 128 + c];
      F[r * 256 + half * 128 + c] = fmaf(g, b - a, a);
    }
  }
  __syncthreads();

  {
    const float4* W4 = (const float4*)(wsb + OFF_FW4);
    const float* F = xu;
    float acc[8];
#pragma unroll
    for (int r = 0; r < 8; ++r) acc[r] = 0.f;
    for (int j = 0; j < 256; j += 4) {
      float4 w = W4[(j >> 2) * 256 + t];
#pragma unroll
      for (int r = 0; r < 8; ++r) {
        float4 fv = *(const float4*)&F[r * 256 + j];
        acc[r] = fmaf(w.x, fv.x, acc[r]);
        acc[r] = fmaf(w.y, fv.y, acc[r]);
        acc[r] = fmaf(w.z, fv.z, acc[r]);
        acc[r] = fmaf(w.w, fv.w, acc[r]);
      }
    }
    float* H = xt;
    float bias = ff_b[t];
#pragma unroll
    for (int r = 0; r < 8; ++r) H[r * 256 + t] = acc[r] + bias;
  }
  __syncthreads();

  {
    const float* H = xt;
    int r = t >> 5, q = t & 31;
    const float* Hr = H + r * 256 + q * 8;
    float s1 = 0.f, s2 = 0.f;
#pragma unroll
    for (int i = 0; i < 8; ++i) {
      float v = Hr[i];
      s1 += v;
      s2 += v * v;
    }
#pragma unroll
    for (int off = 1; off < 32; off <<= 1) {
      s1 += __shfl_xor(s1, off);
      s2 += __shfl_xor(s2, off);
    }
    float mu = s1 * (1.f / 256.f);
    float var = s2 * (1.f / 256.f) - mu * mu;
    float rstd = rsqrtf(var + 1e-5f);
    float* op = out + (row0 + r) * 256 + q * 8;
#pragma unroll
    for (int i = 0; i < 8; ++i) {
      float v = (Hr[i] - mu) * rstd * ln_g[q * 8 + i] + ln_b[q * 8 + i];
      op[i] = v > 0.f ? v : 0.f;
    }
  }
}

}  // namespace

extern "C" void kernel_launch(void* const* d_in, const int* in_sizes, int n_in,
                              void* d_out, int out_size, void* d_ws, size_t ws_size,
                              hipStream_t stream) {
  const float* text = (const float*)d_in[0];
  const float* user = (const float*)d_in[1];
  const float* tm_w = (const float*)d_in[2];
  const float* tm_b = (const float*)d_in[3];
  const float* um_w = (const float*)d_in[4];
  const float* um_b = (const float*)d_in[5];
  const float* ipw = (const float*)d_in[6];
  const float* ipb = (const float*)d_in[7];
  const float* opw = (const float*)d_in[8];
  const float* opb = (const float*)d_in[9];
  const float* tg_w = (const float*)d_in[10];
  const float* tg_b = (const float*)d_in[11];
  const float* ug_w = (const float*)d_in[12];
  const float* ug_b = (const float*)d_in[13];
  const float* ff_w = (const float*)d_in[14];
  const float* ff_b = (const float*)d_in[15];
  const float* ln_g = (const float*)d_in[16];
  const float* ln_b = (const float*)d_in[17];
  char* wsb = (char*)d_ws;
  float* out = (float*)d_out;

  // common precompute
  k_combine<<<256, 256, 0, stream>>>(ipw, opw, wsb);
  k_combine_bias<<<2, 256, 0, stream>>>(ipb, opb, opw, wsb);
  k_bias_tu<<<2, 256, 0, stream>>>(tm_b, um_b, wsb);
  k_mt4<<<768, 256, 0, stream>>>(tm_w, wsb);
  k_mu4<<<256, 256, 0, stream>>>(um_w, wsb);

  if ((long)ws_size >= WS_NEED) {
    // fast path: gate-folded MFMA front -> F -> ff MFMA (H over F) -> LN
    float* Fg = (float*)(wsb + OFF_F);
    k_mt_hl<<<768, 256, 0, stream>>>(tm_w, wsb);
    k_mu_hl<<<256, 256, 0, stream>>>(um_w, wsb);
    k_gt<<<768, 256, 0, stream>>>(tg_w, ug_w, wsb);
    k_gu<<<256, 256, 0, stream>>>(tg_w, ug_w, wsb);
    k_gbias<<<1, 256, 0, stream>>>(tg_w, tg_b, ug_w, ug_b, wsb);
    k_ff_hl<<<256, 256, 0, stream>>>(ff_w, wsb);
    k_s12g<<<2048, 512, 0, stream>>>(text, user, wsb, Fg);
    k_ff32<<<2048, 512, 0, stream>>>(Fg, wsb, ff_b);
    k_ln<<<4096, 256, 0, stream>>>(Fg, ln_g, ln_b, out);
  } else {
    // fallback: R5 fused scalar (known-pass)
    k_pack_gw4<<<256, 256, 0, stream>>>(tg_w, ug_w, wsb);
    k_transpose4<<<256, 256, 0, stream>>>(ff_w, (float*)(wsb + OFF_FW4), 256, 256);
    k_main5<<<8192, 256, 0, stream>>>(text, user, wsb, tg_b, ug_b, ff_b, ln_g, ln_b, out);
  }
}